// Round 8
// baseline (21.491 us; speedup 1.0000x reference)
//
#include <hip/hip_runtime.h>
#include <math.h>

#define NB 8192
#define NC 1024
#define NS 16

// log_ndtr nearest-neighbor table: x_i = -9.5 + i/128, entries 0..NTR-1 real
#define NT   2464
#define NTR  2461
#define C0   48          // skip row if count(l_j >= l_y) - 1 >= C0
#define BMAXF 1984.0f    // base-index clamp hi (so base+476 <= 2460)
#define UBIAS 978.5f     // 9.5*128 - 238 + 0.5 (fold: round + okint[0] bias)

// OFFK[k] = round(t_k*128) + 238, t_k = ndtri((k+0.5)/16) quantized to grid
constexpr int OFFK[16] = {0, 69, 109, 139, 164, 187, 208, 228,
                          248, 268, 289, 312, 337, 367, 407, 476};

// ws layout (float/int indices):
// [2] (int) finalize ticket
// [16..1039]    per-block partial sum (1024)
// [1040..2063]  per-block partial sumsq (1024)
// [2064..3087]  (int) per-region live count (1024 regions of 8 rows)
// [3088..11279] (int) per-region live row ids (1024*8)
// [11280..11407] per-k_main-block prob partials (128)
// [11408..11408+NT) table
#define TICKET 2
#define PSUM  16
#define PSQ   1040
#define RCNT  2064
#define RLIST 3088
#define PART  11280
#define TAB   11408
#define NBLK_MAIN 128

__device__ __forceinline__ float log_ndtr_f(float x) {
    float e = erfcf(-x * 0.70710678118654752f);
    if (e > 1e-37f) return __logf(0.5f * e);
    return -0.5f * x * x - 0.91893853320467274f - __logf(-x);
}

__global__ __launch_bounds__(256) void k_pre(const float* __restrict__ logits,
                                             const int* __restrict__ labels,
                                             float* __restrict__ ws) {
    const int bid = blockIdx.x;
    if (bid >= 1024) {
        // float table build + ticket reset
        if (bid == 1024 && threadIdx.x == 0) ((int*)ws)[TICKET] = 0;
        int i = (bid - 1024) * 256 + threadIdx.x;
        if (i < NT) {
            int ii = i < NTR ? i : (NTR - 1);
            float x = -9.5f + (float)ii * (1.0f / 128.0f);
            ws[TAB + i] = log_ndtr_f(x);
        }
        return;
    }
    const int w = threadIdx.x >> 6, l = threadIdx.x & 63;
    const float4* lf4 = (const float4*)logits;
    __shared__ int flags[8];
    __shared__ float bs[4], bss[4];
    float s = 0.0f, ss = 0.0f;
    for (int rr = 0; rr < 2; ++rr) {
        const int row = bid * 8 + w * 2 + rr;
        const float tgt = logits[row * NC + labels[row]];
        int cnt = 0;
        #pragma unroll
        for (int i = 0; i < 4; ++i) {
            float4 v = lf4[row * (NC / 4) + l + 64 * i];
            s  += v.x + v.y + v.z + v.w;
            ss += v.x * v.x + v.y * v.y + v.z * v.z + v.w * v.w;
            cnt += (v.x >= tgt) + (v.y >= tgt) + (v.z >= tgt) + (v.w >= tgt);
        }
        #pragma unroll
        for (int m = 32; m; m >>= 1) cnt += __shfl_xor(cnt, m, 64);
        if (l == 0) flags[w * 2 + rr] = ((cnt - 1) < C0);   // cnt-1: exclude self
    }
    #pragma unroll
    for (int m = 32; m; m >>= 1) {
        s  += __shfl_xor(s,  m, 64);
        ss += __shfl_xor(ss, m, 64);
    }
    if (l == 0) { bs[w] = s; bss[w] = ss; }
    __syncthreads();
    if (threadIdx.x == 0) {
        ws[PSUM + bid] = bs[0] + bs[1] + bs[2] + bs[3];
        ws[PSQ + bid]  = bss[0] + bss[1] + bss[2] + bss[3];
        int* wsi = (int*)ws;
        int n = 0;
        #pragma unroll
        for (int i = 0; i < 8; ++i)
            if (flags[i]) wsi[RLIST + bid * 8 + (n++)] = bid * 8 + i;
        wsi[RCNT + bid] = n;
    }
}

__global__ __launch_bounds__(256) void k_main(const float* __restrict__ logits,
                                              const int* __restrict__ labels,
                                              const float* __restrict__ temp,
                                              float* __restrict__ ws,
                                              float* __restrict__ out) {
    const int bid = blockIdx.x, tid = threadIdx.x;
    const int* wsi = (const int*)ws;
    const int w = tid >> 6, l = tid & 63;

    __shared__ float lt[NT];
    __shared__ int   P[1024];
    __shared__ int   wtot[4];
    __shared__ float rs[4], rss[4];
    __shared__ float shInv;
    __shared__ float wprob[4];
    __shared__ int   shLast;

    // cooperative table load (L2-hot)
    float4* lt4 = (float4*)lt;
    const float4* gt4 = (const float4*)(ws + TAB);
    for (int i = tid; i < NT / 4; i += 256) lt4[i] = gt4[i];

    // ---- global prefix sum of region counts (redundant per block, L2-hot) ----
    int c4[4];
    const int b4 = tid * 4;
    #pragma unroll
    for (int j = 0; j < 4; ++j) c4[j] = wsi[RCNT + b4 + j];
    int s4 = c4[0] + c4[1] + c4[2] + c4[3];
    // inclusive wave scan of s4
    int v = s4;
    #pragma unroll
    for (int off = 1; off < 64; off <<= 1) {
        int u = __shfl_up(v, off, 64);
        if (l >= off) v += u;
    }
    if (l == 63) wtot[w] = v;

    // ---- inv_s from the 1024 partials ----
    float s  = ws[PSUM + tid] + ws[PSUM + 256 + tid] + ws[PSUM + 512 + tid] + ws[PSUM + 768 + tid];
    float ss = ws[PSQ + tid]  + ws[PSQ + 256 + tid]  + ws[PSQ + 512 + tid]  + ws[PSQ + 768 + tid];
    #pragma unroll
    for (int m = 32; m; m >>= 1) {
        s  += __shfl_xor(s,  m, 64);
        ss += __shfl_xor(ss, m, 64);
    }
    if (l == 0) { rs[w] = s; rss[w] = ss; }
    __syncthreads();

    int wbase = 0;
    #pragma unroll
    for (int ww = 0; ww < 4; ++ww) if (ww < w) wbase += wtot[ww];
    int ex = wbase + v - s4;   // exclusive prefix for this thread's 4 regions
    P[b4 + 0] = ex;
    P[b4 + 1] = ex + c4[0];
    P[b4 + 2] = ex + c4[0] + c4[1];
    P[b4 + 3] = ex + c4[0] + c4[1] + c4[2];
    const int Ntot = wtot[0] + wtot[1] + wtot[2] + wtot[3];

    if (tid == 0) {
        float S1 = rs[0] + rs[1] + rs[2] + rs[3];
        float S2 = rss[0] + rss[1] + rss[2] + rss[3];
        const float N = (float)NB * (float)NC;
        float var = (S2 - S1 * S1 / N) / (N - 1.0f);
        shInv = 128.0f / (sqrtf(var) * temp[0]);
    }
    __syncthreads();
    const float s128 = shInv;

    const float4* lf4 = (const float4*)logits;
    float waveProb = 0.0f;
    const int gwave = bid * 4 + w;   // 512 waves total

    for (int i = gwave; i < Ntot; i += NBLK_MAIN * 4) {
        // binary search: last region with P[reg] <= i
        int lo = 0, hi = 1023;
        while (lo < hi) {
            int mid = (lo + hi + 1) >> 1;
            if (P[mid] <= i) lo = mid; else hi = mid - 1;
        }
        const int row = wsi[RLIST + lo * 8 + (i - P[lo])];

        const float tgt = logits[row * NC + labels[row]];
        const float A = fmaf(tgt, s128, UBIAS);
        float a[16];
        #pragma unroll
        for (int k = 0; k < 16; ++k) a[k] = 0.0f;
        #pragma unroll
        for (int ii = 0; ii < 4; ++ii) {
            float4 vv4 = lf4[row * (NC / 4) + l + 64 * ii];
            float vv[4] = {vv4.x, vv4.y, vv4.z, vv4.w};
            #pragma unroll
            for (int j = 0; j < 4; ++j) {
                float u = fmaf(vv[j], -s128, A);
                u = fminf(fmaxf(u, 0.0f), BMAXF);
                int bi = (int)u;
                #pragma unroll
                for (int k = 0; k < 16; ++k) a[k] += lt[bi + OFFK[k]];
            }
        }
        #pragma unroll
        for (int k = 0; k < 16; ++k) {
            #pragma unroll
            for (int m = 32; m; m >>= 1) a[k] += __shfl_xor(a[k], m, 64);
        }
        // exact y-term cancellation: same float ops as the j==y column
        float uy = fmaf(tgt, -s128, A);
        uy = fminf(fmaxf(uy, 0.0f), BMAXF);
        int by = (int)uy;
        float prob = 0.0f;
        #pragma unroll
        for (int k = 0; k < 16; ++k) prob += __expf(a[k] - lt[by + OFFK[k]]);
        waveProb += prob * (1.0f / 16.0f);
    }

    if (l == 0) wprob[w] = waveProb;
    __syncthreads();

    // ---- fused finalize: 128-block ticket, deterministic last-block reduce ----
    if (tid == 0) {
        float part = wprob[0] + wprob[1] + wprob[2] + wprob[3];
        __hip_atomic_store(&ws[PART + bid], part, __ATOMIC_RELAXED,
                           __HIP_MEMORY_SCOPE_AGENT);
        int t = __hip_atomic_fetch_add((int*)ws + TICKET, 1, __ATOMIC_ACQ_REL,
                                       __HIP_MEMORY_SCOPE_AGENT);
        shLast = (t == NBLK_MAIN - 1);
    }
    __syncthreads();
    if (shLast) {
        float p = 0.0f;
        if (tid < NBLK_MAIN)
            p = __hip_atomic_load(&ws[PART + tid], __ATOMIC_RELAXED,
                                  __HIP_MEMORY_SCOPE_AGENT);
        #pragma unroll
        for (int m = 32; m; m >>= 1) p += __shfl_xor(p, m, 64);
        if (l == 0) wprob[w] = p;
        __syncthreads();
        if (tid == 0)
            out[0] = 1.0f - (wprob[0] + wprob[1]) * (1.0f / (float)NB);
    }
}

extern "C" void kernel_launch(void* const* d_in, const int* in_sizes, int n_in,
                              void* d_out, int out_size, void* d_ws, size_t ws_size,
                              hipStream_t stream) {
    const float* logits = (const float*)d_in[0];
    const int*   labels = (const int*)d_in[1];
    const float* temp   = (const float*)d_in[2];
    float* ws  = (float*)d_ws;
    float* out = (float*)d_out;

    hipLaunchKernelGGL(k_pre,  dim3(1024 + (NT + 255) / 256), dim3(256), 0, stream,
                       logits, labels, ws);
    hipLaunchKernelGGL(k_main, dim3(NBLK_MAIN), dim3(256), 0, stream,
                       logits, labels, temp, ws, out);
}